// Round 8
// baseline (445.845 us; speedup 1.0000x reference)
//
#include <hip/hip_runtime.h>

#define B_DIM 2048
#define IN_DIM 1024
#define M_DIM 256
#define P_DIM 32896            // 256*257/2
#define RTP_B 40960            // elements per batch: row-tile padded, chunk-XOR swizzled
#define CRTP_BYTES (167772160) // 2048*40960*2
#define WB_BYTES   (67371008)  // 32896*1024*2

typedef __attribute__((ext_vector_type(8))) short short8;
typedef __attribute__((ext_vector_type(4))) float f32x4;

#define GLD16(gsrc, ldst) __builtin_amdgcn_global_load_lds(                    \
    (const __attribute__((address_space(1))) unsigned int*)(gsrc),             \
    (__attribute__((address_space(3))) unsigned int*)(ldst), 16, 0, 0)

__device__ __forceinline__ unsigned short f2bf(float f) {
    unsigned int u = __float_as_uint(f);
    u += 0x7FFFu + ((u >> 16) & 1u);          // RNE to bf16
    return (unsigned short)(u >> 16);
}
// base offset of row r: tile g padded to (g+1)*64 cols (rows 128B-aligned)
__device__ __forceinline__ int rtp0(int r) {
    const int g = r >> 6;
    return 2048 * g * (g + 1) + (r & 63) * ((g + 1) << 6);
}
// element (r,c): 8-el chunk index XOR'd by (r&7)
__device__ __forceinline__ int rtp_off(int r, int c) {
    return rtp0(r) + (((c >> 3) ^ (r & 7)) << 3) + (c & 7);
}

// ---------------- merged prep: W cvt | X cvt | Crtp pad zero ----------
#define NW_BLK 8224            // 8224*1024 float4 = 32896*1024/4
#define NX_BLK 512             // 512*1024  float4 = 2048*1024/4
#define NZ_BLK 2048
__global__ void prep_all(const float* __restrict__ X, const float* __restrict__ W,
                         unsigned short* __restrict__ Xhi, unsigned short* __restrict__ Wb,
                         unsigned short* __restrict__ Crtp) {
    const int bid = blockIdx.x, tid = threadIdx.x;
    if (bid < NW_BLK) {
#pragma unroll
        for (int u = 0; u < 4; ++u) {
            const int i = bid * 1024 + u * 256 + tid;
            float4 v = reinterpret_cast<const float4*>(W)[i];
            ushort4 h;
            h.x = f2bf(v.x); h.y = f2bf(v.y); h.z = f2bf(v.z); h.w = f2bf(v.w);
            reinterpret_cast<ushort4*>(Wb)[i] = h;
        }
    } else if (bid < NW_BLK + NX_BLK) {
#pragma unroll
        for (int u = 0; u < 4; ++u) {
            const int i = (bid - NW_BLK) * 1024 + u * 256 + tid;
            float4 v = reinterpret_cast<const float4*>(X)[i];
            ushort4 h;
            h.x = f2bf(v.x); h.y = f2bf(v.y); h.z = f2bf(v.z); h.w = f2bf(v.w);
            reinterpret_cast<ushort4*>(Xhi)[i] = h;
        }
    } else {
        const int b = bid - NW_BLK - NX_BLK;            // batch
        const int r = tid;                               // row
        const int g = r >> 6;
        const int nch = (g + 1) << 3;
        const int xm = r & 7;
        unsigned short* base = Crtp + (size_t)b * RTP_B + rtp0(r);
        const int pc = (r >> 3) ^ xm;
        for (int c = r + 1; (c >> 3) == (r >> 3); ++c) base[(pc << 3) + (c & 7)] = 0;
        const uint4 z = make_uint4(0u, 0u, 0u, 0u);
        for (int cc = (r >> 3) + 1; cc < nch; ++cc)
            *reinterpret_cast<uint4*>(&base[(cc ^ xm) << 3]) = z;
    }
}

// ---------------- Stage 1: C = Xhi @ Wb^T + bias, diag-ReLU, store rtp bf16 ----------
// Main (blocks 0..1023): BM=BN=256, 8 waves (2M x 4N, wave 128x64), BK=32 slabs,
// 4-slot LDS ring (4 x 32KB), 3-slab lookahead, counted vmcnt(8), 2 phases/slab
// {ds_read || 2xGLD16 -> barrier -> setprio 16 MFMA}. 64B row stride => reads are a
// perfect 32-bank spread, no swizzle. Grid: rtile = bid&7 (XCD-resident 0.5MB X slice),
// panel = bid>>3 (all XCDs walk panels together, W L3-shared). 1024 = 4.000 rounds.
// Tail (blocks 1024..1087): cols 32768..32895, LDS-free 32x16 micro-GEMM, runs on
// first-freed CUs during the main grid's last round.
__global__ __launch_bounds__(512) void gemm1_kernel(
    const unsigned short* __restrict__ Xhi,
    const unsigned short* __restrict__ Wb, const float* __restrict__ bias,
    unsigned short* __restrict__ Crtp)
{
    __shared__ unsigned short lds[65536];          // 4 slots x (A 8192 | B 8192) els

    const int bid  = blockIdx.x;
    const int tid  = threadIdx.x;
    const int lane = tid & 63;
    const int wid  = tid >> 6;                     // 0..7
    const int lr16 = lane & 15;
    const int kq   = lane >> 4;                    // 16B k-chunk 0..3

    if (bid >= 1024) {                             // ---- tail path ----
        const int tb = bid - 1024;                 // 0..63
        const int r0 = tb << 5;                    // 32 rows per block
        f32x4 acc0 = (f32x4){0.f,0.f,0.f,0.f}, acc1 = (f32x4){0.f,0.f,0.f,0.f};
        const unsigned short* pa0 = Xhi + (size_t)(r0 + lr16) * IN_DIM + kq * 8;
        const unsigned short* pa1 = pa0 + 16 * IN_DIM;
        const unsigned short* pb  = Wb + (size_t)(32768 + (wid << 4) + lr16) * IN_DIM + kq * 8;
#pragma unroll 4
        for (int s = 0; s < 32; ++s) {
            short8 a0 = *reinterpret_cast<const short8*>(pa0 + s * 32);
            short8 a1 = *reinterpret_cast<const short8*>(pa1 + s * 32);
            short8 b0 = *reinterpret_cast<const short8*>(pb + s * 32);
            acc0 = __builtin_amdgcn_mfma_f32_16x16x32_bf16(a0, b0, acc0, 0, 0, 0);
            acc1 = __builtin_amdgcn_mfma_f32_16x16x32_bf16(a1, b0, acc1, 0, 0, 0);
        }
        const int p = 32768 + (wid << 4) + lr16;   // < P_DIM always
        const float t = sqrtf((float)(8 * p + 1));
        const int rt = (int)((t - 1.0f) * 0.5f + 0.001f);
        const int ct = p - ((rt * (rt + 1)) >> 1);
        const int off = rtp_off(rt, ct);
        const bool diag = (ct == rt);
        const float bvs = bias[p];
#pragma unroll
        for (int m = 0; m < 2; ++m) {
            const f32x4 a = m ? acc1 : acc0;
#pragma unroll
            for (int q = 0; q < 4; ++q) {
                const int brow = r0 + (m << 4) + (kq << 2) + q;
                float v = a[q] + bvs;
                if (diag) v = fmaxf(v, 0.f);
                Crtp[(size_t)brow * RTP_B + off] = f2bf(v);
            }
        }
        return;
    }

    // ---- main path ----
    const int row0 = (bid & 7) << 8;
    const int col0 = (bid >> 3) << 8;
    const int wr   = wid >> 2;                     // 0..1 (M half)
    const int wn   = wid & 3;                      // 0..3 (N quarter)

    // staging bases: round i covers rows [128i,128i+128); wave stages rows +wid*16..+16
    const int srow4 = lane >> 2;                   // 0..15
    const int sc4   = lane & 3;                    // 16B chunk within K=32
    const unsigned short* pA = Xhi + (size_t)(row0 + (wid << 4) + srow4) * IN_DIM + sc4 * 8;
    const unsigned short* pB = Wb  + (size_t)(col0 + (wid << 4) + srow4) * IN_DIM + sc4 * 8;

#define STG_A(s) { const int sl_ = (((s) & 3) << 14);                          \
        GLD16(pA + (size_t)(s) * 32, &lds[sl_ + ((wid << 4) << 5)]);           \
        GLD16(pA + (size_t)128 * IN_DIM + (size_t)(s) * 32,                    \
              &lds[sl_ + ((128 + (wid << 4)) << 5)]); }
#define STG_B(s) { const int sl_ = (((s) & 3) << 14) + 8192;                   \
        GLD16(pB + (size_t)(s) * 32, &lds[sl_ + ((wid << 4) << 5)]);           \
        GLD16(pB + (size_t)128 * IN_DIM + (size_t)(s) * 32,                    \
              &lds[sl_ + ((128 + (wid << 4)) << 5)]); }

    f32x4 acc[8][4];
#pragma unroll
    for (int m = 0; m < 8; ++m)
#pragma unroll
        for (int n = 0; n < 4; ++n) acc[m][n] = (f32x4){0.f, 0.f, 0.f, 0.f};

    STG_A(0); STG_B(0); STG_A(1); STG_B(1); STG_A(2); STG_B(2);

    for (int s = 0; s < 32; ++s) {
        if (s < 30)       asm volatile("s_waitcnt vmcnt(8)" ::: "memory");
        else if (s == 30) asm volatile("s_waitcnt vmcnt(4)" ::: "memory");
        else              asm volatile("s_waitcnt vmcnt(0)" ::: "memory");
        __builtin_amdgcn_s_barrier();
        asm volatile("" ::: "memory");

        const int sl = (s & 3) << 14;
        short8 av[4], bv[4];
        // ---- phase 0: m-frags 0..3, all n ----
#pragma unroll
        for (int m = 0; m < 4; ++m) {
            const int r = (wr << 7) + (m << 4) + lr16;
            av[m] = *reinterpret_cast<const short8*>(&lds[sl + (r << 5) + kq * 8]);
        }
#pragma unroll
        for (int n = 0; n < 4; ++n) {
            const int r = (wn << 6) + (n << 4) + lr16;
            bv[n] = *reinterpret_cast<const short8*>(&lds[sl + 8192 + (r << 5) + kq * 8]);
        }
        if (s < 29) STG_A(s + 3);
        __builtin_amdgcn_s_setprio(1);
#pragma unroll
        for (int m = 0; m < 4; ++m)
#pragma unroll
            for (int n = 0; n < 4; ++n)
                acc[m][n] = __builtin_amdgcn_mfma_f32_16x16x32_bf16(av[m], bv[n], acc[m][n], 0, 0, 0);
        __builtin_amdgcn_s_setprio(0);
        __builtin_amdgcn_s_barrier();
        asm volatile("" ::: "memory");

        // ---- phase 1: m-frags 4..7 ----
#pragma unroll
        for (int m = 0; m < 4; ++m) {
            const int r = (wr << 7) + ((4 + m) << 4) + lr16;
            av[m] = *reinterpret_cast<const short8*>(&lds[sl + (r << 5) + kq * 8]);
        }
        if (s < 29) STG_B(s + 3);
        __builtin_amdgcn_s_setprio(1);
#pragma unroll
        for (int m = 0; m < 4; ++m)
#pragma unroll
            for (int n = 0; n < 4; ++n)
                acc[4 + m][n] = __builtin_amdgcn_mfma_f32_16x16x32_bf16(av[m], bv[n], acc[4 + m][n], 0, 0, 0);
        __builtin_amdgcn_s_setprio(0);
    }
#undef STG_A
#undef STG_B

    // epilogue: D col = lane&15, row = (lane>>4)*4 + reg
#pragma unroll
    for (int n = 0; n < 4; ++n) {
        const int p = col0 + (wn << 6) + (n << 4) + lr16;     // < P_DIM for panels 0..127
        const float t = sqrtf((float)(8 * p + 1));
        const int rt = (int)((t - 1.0f) * 0.5f + 0.001f);     // tril row
        const int ct = p - ((rt * (rt + 1)) >> 1);            // tril col
        const int off = rtp_off(rt, ct);                      // swizzled position
        const bool diag = (ct == rt);
        const float bvs = bias[p];
#pragma unroll
        for (int m = 0; m < 8; ++m) {
#pragma unroll
            for (int q = 0; q < 4; ++q) {
                const int brow = row0 + (wr << 7) + (m << 4) + (kq << 2) + q;
                float v = acc[m][n][q] + bvs;
                if (diag) v = fmaxf(v, 0.f);
                Crtp[(size_t)brow * RTP_B + off] = f2bf(v);
            }
        }
    }
}

// ---------------- Stage 2: O[b] = L_b @ L_b^T, LDS-staged (80 KB -> 2 blocks/CU) ------
__global__ __launch_bounds__(256) void syrk_kernel(
    const unsigned short* __restrict__ Crtp, float* __restrict__ O)
{
    __shared__ unsigned short Lt[RTP_B];       // 81920 B exactly -> 2 blocks/CU
    const int tid  = threadIdx.x;
    const int lane = tid & 63;
    const int wid  = tid >> 6;
    const int b    = blockIdx.x;
    const unsigned short* Cb = Crtp + (size_t)b * RTP_B;

#pragma unroll
    for (int i = 0; i < 20; ++i) {
        const int g = wid * 20 + i;
        GLD16(Cb + g * 512 + (lane << 3), &Lt[g * 512]);
    }
    __syncthreads();

    const int lr16 = lane & 15;
    const int kc   = lane >> 4;
    float* Ob = O + (size_t)b * (M_DIM * M_DIM);

    const unsigned char LIST[4][5] = {
        {0x33, 0x22, 0x00, 0x00, 0x00},
        {0x23, 0x32, 0x01, 0x10, 0x00},
        {0x11, 0x12, 0x21, 0x02, 0x00},
        {0x13, 0x31, 0x03, 0x30, 0x20}};
    const int CNT[4] = {3, 4, 4, 5};
    const int cnt = CNT[wid];

    for (int tt = 0; tt < cnt; ++tt) {
        const int code = LIST[wid][tt];
        const int ti = code >> 4, tj = code & 15;

        int baseA[4], xA[4], baseB[4], xB[4];
#pragma unroll
        for (int m = 0; m < 4; ++m) {
            const int ia = (ti << 6) + (m << 4) + lr16;
            const int jb = (tj << 6) + (m << 4) + lr16;
            baseA[m] = rtp0(ia); xA[m] = ia & 7;
            baseB[m] = rtp0(jb); xB[m] = jb & 7;
        }
        f32x4 acc[4][4];
#pragma unroll
        for (int m = 0; m < 4; ++m)
#pragma unroll
            for (int n = 0; n < 4; ++n) acc[m][n] = (f32x4){0.f, 0.f, 0.f, 0.f};

        const int kmax = ti < tj ? ti : tj;
        for (int kt = 0; kt <= kmax; ++kt) {
#pragma unroll
            for (int s = 0; s < 2; ++s) {
                const int cidx = (kt << 3) + (s << 2) + kc;   // 8-el chunk index
                short8 a[4], bb[4];
#pragma unroll
                for (int m = 0; m < 4; ++m)
                    a[m] = *reinterpret_cast<const short8*>(&Lt[baseA[m] + ((cidx ^ xA[m]) << 3)]);
#pragma unroll
                for (int n = 0; n < 4; ++n)
                    bb[n] = *reinterpret_cast<const short8*>(&Lt[baseB[n] + ((cidx ^ xB[n]) << 3)]);
#pragma unroll
                for (int m = 0; m < 4; ++m)
#pragma unroll
                    for (int n = 0; n < 4; ++n)
                        acc[m][n] = __builtin_amdgcn_mfma_f32_16x16x32_bf16(a[m], bb[n], acc[m][n], 0, 0, 0);
            }
        }
#pragma unroll
        for (int m = 0; m < 4; ++m) {
            const int i0 = (ti << 6) + (m << 4) + (kc << 2);
#pragma unroll
            for (int n = 0; n < 4; ++n) {
                const int j = (tj << 6) + (n << 4) + lr16;
#pragma unroll
                for (int q = 0; q < 4; ++q)
                    __builtin_nontemporal_store(acc[m][n][q], &Ob[(size_t)(i0 + q) * M_DIM + j]);
            }
        }
    }
}

extern "C" void kernel_launch(void* const* d_in, const int* in_sizes, int n_in,
                              void* d_out, int out_size, void* d_ws, size_t ws_size,
                              hipStream_t stream)
{
    (void)in_sizes; (void)n_in; (void)out_size; (void)ws_size;
    const float* x    = (const float*)d_in[0];
    const float* W    = (const float*)d_in[1];
    const float* bias = (const float*)d_in[2];
    float* O = (float*)d_out;

    char* ws = (char*)d_ws;
    unsigned short* Crtp = (unsigned short*)ws;
    unsigned short* Wb   = (unsigned short*)(ws + CRTP_BYTES);
    unsigned short* Xhi  = (unsigned short*)(ws + CRTP_BYTES + WB_BYTES);

    prep_all<<<dim3(NW_BLK + NX_BLK + NZ_BLK), dim3(256), 0, stream>>>(
        x, W, Xhi, Wb, Crtp);
    gemm1_kernel<<<dim3(1088), dim3(512), 0, stream>>>(Xhi, Wb, bias, Crtp);
    syrk_kernel<<<dim3(B_DIM), dim3(256), 0, stream>>>(Crtp, O);
}

// Round 9
// 419.149 us; speedup vs baseline: 1.0637x; 1.0637x over previous
//
#include <hip/hip_runtime.h>

#define B_DIM 2048
#define IN_DIM 1024
#define M_DIM 256
#define P_DIM 32896            // 256*257/2
#define RTP_B 40960            // elements per batch: row-tile padded, chunk-XOR swizzled
#define CRTP_BYTES (167772160) // 2048*40960*2
#define WB_BYTES   (67371008)  // 32896*1024*2

typedef __attribute__((ext_vector_type(8))) short short8;
typedef __attribute__((ext_vector_type(4))) float f32x4;

#define GLD16(gsrc, ldst) __builtin_amdgcn_global_load_lds(                    \
    (const __attribute__((address_space(1))) unsigned int*)(gsrc),             \
    (__attribute__((address_space(3))) unsigned int*)(ldst), 16, 0, 0)

__device__ __forceinline__ unsigned short f2bf(float f) {
    unsigned int u = __float_as_uint(f);
    u += 0x7FFFu + ((u >> 16) & 1u);          // RNE to bf16
    return (unsigned short)(u >> 16);
}
// base offset of row r: tile g padded to (g+1)*64 cols (rows 128B-aligned)
__device__ __forceinline__ int rtp0(int r) {
    const int g = r >> 6;
    return 2048 * g * (g + 1) + (r & 63) * ((g + 1) << 6);
}
// element (r,c): 8-el chunk index XOR'd by (r&7)
__device__ __forceinline__ int rtp_off(int r, int c) {
    return rtp0(r) + (((c >> 3) ^ (r & 7)) << 3) + (c & 7);
}

// ---------------- merged prep: W cvt | X cvt | Crtp pad zero (single launch) ---------
#define NW_BLK 8224            // 8224*1024 float4 = 32896*1024/4
#define NX_BLK 512             // 512*1024  float4 = 2048*1024/4
#define NZ_BLK 2048
__global__ void prep_all(const float* __restrict__ X, const float* __restrict__ W,
                         unsigned short* __restrict__ Xhi, unsigned short* __restrict__ Wb,
                         unsigned short* __restrict__ Crtp) {
    const int bid = blockIdx.x, tid = threadIdx.x;
    if (bid < NW_BLK) {
#pragma unroll
        for (int u = 0; u < 4; ++u) {
            const int i = bid * 1024 + u * 256 + tid;
            float4 v = reinterpret_cast<const float4*>(W)[i];
            ushort4 h;
            h.x = f2bf(v.x); h.y = f2bf(v.y); h.z = f2bf(v.z); h.w = f2bf(v.w);
            reinterpret_cast<ushort4*>(Wb)[i] = h;
        }
    } else if (bid < NW_BLK + NX_BLK) {
#pragma unroll
        for (int u = 0; u < 4; ++u) {
            const int i = (bid - NW_BLK) * 1024 + u * 256 + tid;
            float4 v = reinterpret_cast<const float4*>(X)[i];
            ushort4 h;
            h.x = f2bf(v.x); h.y = f2bf(v.y); h.z = f2bf(v.z); h.w = f2bf(v.w);
            reinterpret_cast<ushort4*>(Xhi)[i] = h;
        }
    } else {
        const int b = bid - NW_BLK - NX_BLK;            // batch
        const int r = tid;                               // row
        const int g = r >> 6;
        const int nch = (g + 1) << 3;
        const int xm = r & 7;
        unsigned short* base = Crtp + (size_t)b * RTP_B + rtp0(r);
        const int pc = (r >> 3) ^ xm;
        for (int c = r + 1; (c >> 3) == (r >> 3); ++c) base[(pc << 3) + (c & 7)] = 0;
        const uint4 z = make_uint4(0u, 0u, 0u, 0u);
        for (int cc = (r >> 3) + 1; cc < nch; ++cc)
            *reinterpret_cast<uint4*>(&base[(cc ^ xm) << 3]) = z;
    }
}

// ---------------- Stage 1: C = Xhi @ Wb^T + bias, diag-ReLU, store rtp bf16 ----------
// BM=256, BN=128, BK=64. 512 threads = 8 waves (4M x 2N), wave tile 64x64.
// Triple-buffered LDS, prefetch depth 2, counted vmcnt(6), 1 barrier/iter, setprio.
// Grid 2080 = 8 XCDs x 260; per XCD: 4 row-tiles (2 MB X slice, L2-resident) x 65
// W panels streamed once (4 consecutive same-XCD blocks share each panel).
__global__ __launch_bounds__(512) void gemm1_kernel(
    const unsigned short* __restrict__ Xhi,
    const unsigned short* __restrict__ Wb, const float* __restrict__ bias,
    unsigned short* __restrict__ Crtp)
{
    __shared__ unsigned short lds[3 * 24576];      // per buf: A 16384 el | B 8192 el

    const int lin = blockIdx.x;
    const int x   = lin & 7;                       // XCD (round-robin dispatch)
    const int j   = lin >> 3;                      // 0..259 within XCD
    const int rtile = ((x & 1) << 2) + (j & 3);    // 0..7
    const int panel = (x >> 1) * 65 + (j >> 2);    // 0..259
    if (panel >= 257) return;
    const int row0 = rtile << 8;
    const int col0 = panel << 7;

    const int tid  = threadIdx.x;
    const int lane = tid & 63;
    const int wid  = tid >> 6;                     // 0..7
    const int wr   = wid >> 1;                     // 0..3
    const int wc   = wid & 1;                      // 0..1
    const int lr16 = lane & 15;
    const int kc   = lane >> 4;

    // staging: 48 x 1KB chunks per K-tile (A = chunks 0..31, B = 32..47);
    // wave stages chunks [6*wid, 6*wid+6). lane -> row lane>>3, 16B-chunk pre-XOR'd.
    const int srow = lane >> 3;
    const int sch  = (lane & 7) ^ srow;
    const unsigned short* gsrc[6];
    int loff[6];
#pragma unroll
    for (int i = 0; i < 6; ++i) {
        const int c = 6 * wid + i;
        if (c < 32) {
            gsrc[i] = Xhi + (size_t)(row0 + c * 8 + srow) * IN_DIM + (sch << 3);
            loff[i] = c * 512;
        } else {
            gsrc[i] = Wb + (size_t)(col0 + (c - 32) * 8 + srow) * IN_DIM + (sch << 3);
            loff[i] = 16384 + (c - 32) * 512;
        }
    }

#define STAGE(kt, bufo)                                                        \
    {                                                                          \
        _Pragma("unroll")                                                      \
        for (int i = 0; i < 6; ++i)                                            \
            GLD16(gsrc[i] + ((kt) << 6), &lds[(bufo) + loff[i]]);              \
    }

    f32x4 acc[4][4];
#pragma unroll
    for (int m = 0; m < 4; ++m)
#pragma unroll
        for (int n = 0; n < 4; ++n) acc[m][n] = (f32x4){0.f, 0.f, 0.f, 0.f};

    int o0 = 0, o1 = 24576, o2 = 49152;
    STAGE(0, o0);
    STAGE(1, o1);

    for (int it = 0; it < 16; ++it) {
        if (it < 15) asm volatile("s_waitcnt vmcnt(6)" ::: "memory");
        else         asm volatile("s_waitcnt vmcnt(0)" ::: "memory");
        __builtin_amdgcn_s_barrier();
        asm volatile("" ::: "memory");             // keep ds_reads below the barrier

        const int cb = o0;
        // ---- phase 0: k-half s=0 ----
        short8 av[4], bv[4];
#pragma unroll
        for (int m = 0; m < 4; ++m) {
            const int r = (wr << 6) + (m << 4) + lr16;
            av[m] = *reinterpret_cast<const short8*>(&lds[cb + r * 64 + (kc ^ (r & 7)) * 8]);
        }
#pragma unroll
        for (int n = 0; n < 4; ++n) {
            const int r = (wc << 6) + (n << 4) + lr16;
            bv[n] = *reinterpret_cast<const short8*>(&lds[cb + 16384 + r * 64 + (kc ^ (r & 7)) * 8]);
        }
        if (it < 14) STAGE(it + 2, o2);            // prefetch depth 2
        __builtin_amdgcn_s_setprio(1);
#pragma unroll
        for (int m = 0; m < 4; ++m)
#pragma unroll
            for (int n = 0; n < 4; ++n)
                acc[m][n] = __builtin_amdgcn_mfma_f32_16x16x32_bf16(av[m], bv[n], acc[m][n], 0, 0, 0);
        __builtin_amdgcn_s_setprio(0);

        // ---- phase 1: k-half s=1 ----
#pragma unroll
        for (int m = 0; m < 4; ++m) {
            const int r = (wr << 6) + (m << 4) + lr16;
            av[m] = *reinterpret_cast<const short8*>(&lds[cb + r * 64 + ((4 + kc) ^ (r & 7)) * 8]);
        }
#pragma unroll
        for (int n = 0; n < 4; ++n) {
            const int r = (wc << 6) + (n << 4) + lr16;
            bv[n] = *reinterpret_cast<const short8*>(&lds[cb + 16384 + r * 64 + ((4 + kc) ^ (r & 7)) * 8]);
        }
        __builtin_amdgcn_s_setprio(1);
#pragma unroll
        for (int m = 0; m < 4; ++m)
#pragma unroll
            for (int n = 0; n < 4; ++n)
                acc[m][n] = __builtin_amdgcn_mfma_f32_16x16x32_bf16(av[m], bv[n], acc[m][n], 0, 0, 0);
        __builtin_amdgcn_s_setprio(0);

        const int t = o0; o0 = o1; o1 = o2; o2 = t;   // rotate ring
    }
#undef STAGE

    // epilogue: D col = lane&15, row = (lane>>4)*4 + reg
#pragma unroll
    for (int n = 0; n < 4; ++n) {
        const int p = col0 + (wc << 6) + (n << 4) + lr16;     // packed tril index
        const float t = sqrtf((float)(8 * p + 1));
        const int rt = (int)((t - 1.0f) * 0.5f + 0.001f);     // tril row
        const int ct = p - ((rt * (rt + 1)) >> 1);            // tril col
        const int off = rtp_off(rt, ct);                      // swizzled position
        const bool diag = (ct == rt);
        const float bvs = bias[p];
#pragma unroll
        for (int m = 0; m < 4; ++m) {
#pragma unroll
            for (int q = 0; q < 4; ++q) {
                const int brow = row0 + (wr << 6) + (m << 4) + (kc << 2) + q;
                float v = acc[m][n][q] + bvs;
                if (diag) v = fmaxf(v, 0.f);
                Crtp[(size_t)brow * RTP_B + off] = f2bf(v);
            }
        }
    }
}

// ---------------- Stage 2: O[b] = L_b @ L_b^T, LDS-staged (80 KB -> 2 blocks/CU) ------
__global__ __launch_bounds__(256) void syrk_kernel(
    const unsigned short* __restrict__ Crtp, float* __restrict__ O)
{
    __shared__ unsigned short Lt[RTP_B];       // 81920 B exactly -> 2 blocks/CU
    const int tid  = threadIdx.x;
    const int lane = tid & 63;
    const int wid  = tid >> 6;
    const int b    = blockIdx.x;
    const unsigned short* Cb = Crtp + (size_t)b * RTP_B;

#pragma unroll
    for (int i = 0; i < 20; ++i) {
        const int g = wid * 20 + i;
        GLD16(Cb + g * 512 + (lane << 3), &Lt[g * 512]);
    }
    __syncthreads();

    const int lr16 = lane & 15;
    const int kc   = lane >> 4;
    float* Ob = O + (size_t)b * (M_DIM * M_DIM);

    const unsigned char LIST[4][5] = {
        {0x33, 0x22, 0x00, 0x00, 0x00},
        {0x23, 0x32, 0x01, 0x10, 0x00},
        {0x11, 0x12, 0x21, 0x02, 0x00},
        {0x13, 0x31, 0x03, 0x30, 0x20}};
    const int CNT[4] = {3, 4, 4, 5};
    const int cnt = CNT[wid];

    for (int tt = 0; tt < cnt; ++tt) {
        const int code = LIST[wid][tt];
        const int ti = code >> 4, tj = code & 15;

        int baseA[4], xA[4], baseB[4], xB[4];
#pragma unroll
        for (int m = 0; m < 4; ++m) {
            const int ia = (ti << 6) + (m << 4) + lr16;
            const int jb = (tj << 6) + (m << 4) + lr16;
            baseA[m] = rtp0(ia); xA[m] = ia & 7;
            baseB[m] = rtp0(jb); xB[m] = jb & 7;
        }
        f32x4 acc[4][4];
#pragma unroll
        for (int m = 0; m < 4; ++m)
#pragma unroll
            for (int n = 0; n < 4; ++n) acc[m][n] = (f32x4){0.f, 0.f, 0.f, 0.f};

        const int kmax = ti < tj ? ti : tj;
        for (int kt = 0; kt <= kmax; ++kt) {
#pragma unroll
            for (int s = 0; s < 2; ++s) {
                const int cidx = (kt << 3) + (s << 2) + kc;   // 8-el chunk index
                short8 a[4], bb[4];
#pragma unroll
                for (int m = 0; m < 4; ++m)
                    a[m] = *reinterpret_cast<const short8*>(&Lt[baseA[m] + ((cidx ^ xA[m]) << 3)]);
#pragma unroll
                for (int n = 0; n < 4; ++n)
                    bb[n] = *reinterpret_cast<const short8*>(&Lt[baseB[n] + ((cidx ^ xB[n]) << 3)]);
#pragma unroll
                for (int m = 0; m < 4; ++m)
#pragma unroll
                    for (int n = 0; n < 4; ++n)
                        acc[m][n] = __builtin_amdgcn_mfma_f32_16x16x32_bf16(a[m], bb[n], acc[m][n], 0, 0, 0);
            }
        }
#pragma unroll
        for (int m = 0; m < 4; ++m) {
            const int i0 = (ti << 6) + (m << 4) + (kc << 2);
#pragma unroll
            for (int n = 0; n < 4; ++n) {
                const int j = (tj << 6) + (n << 4) + lr16;
#pragma unroll
                for (int q = 0; q < 4; ++q)
                    __builtin_nontemporal_store(acc[m][n][q], &Ob[(size_t)(i0 + q) * M_DIM + j]);
            }
        }
    }
}

extern "C" void kernel_launch(void* const* d_in, const int* in_sizes, int n_in,
                              void* d_out, int out_size, void* d_ws, size_t ws_size,
                              hipStream_t stream)
{
    (void)in_sizes; (void)n_in; (void)out_size; (void)ws_size;
    const float* x    = (const float*)d_in[0];
    const float* W    = (const float*)d_in[1];
    const float* bias = (const float*)d_in[2];
    float* O = (float*)d_out;

    char* ws = (char*)d_ws;
    unsigned short* Crtp = (unsigned short*)ws;
    unsigned short* Wb   = (unsigned short*)(ws + CRTP_BYTES);
    unsigned short* Xhi  = (unsigned short*)(ws + CRTP_BYTES + WB_BYTES);

    prep_all<<<dim3(NW_BLK + NX_BLK + NZ_BLK), dim3(256), 0, stream>>>(
        x, W, Xhi, Wb, Crtp);
    gemm1_kernel<<<dim3(2080), dim3(512), 0, stream>>>(Xhi, Wb, bias, Crtp);
    syrk_kernel<<<dim3(B_DIM), dim3(256), 0, stream>>>(Crtp, O);
}

// Round 10
// 334.440 us; speedup vs baseline: 1.3331x; 1.2533x over previous
//
#include <hip/hip_runtime.h>

#define B_DIM 2048
#define IN_DIM 1024
#define M_DIM 256
#define P_DIM 32896            // 256*257/2
#define RTP_B 40960            // elements per batch: row-tile padded, chunk-XOR swizzled
#define CRTP_BYTES (167772160) // 2048*40960*2
#define WQ_BYTES   (33685504)  // 32896*1024 int8
#define XQ_BYTES   (2097152)   // 2048*1024 int8

typedef __attribute__((ext_vector_type(4)))  int   i32x4;
typedef __attribute__((ext_vector_type(4)))  float f32x4;
typedef __attribute__((ext_vector_type(8)))  short short8;

#define GLD16(gsrc, ldst) __builtin_amdgcn_global_load_lds(                    \
    (const __attribute__((address_space(1))) unsigned int*)(gsrc),             \
    (__attribute__((address_space(3))) unsigned int*)(ldst), 16, 0, 0)

__device__ __forceinline__ unsigned short f2bf(float f) {
    unsigned int u = __float_as_uint(f);
    u += 0x7FFFu + ((u >> 16) & 1u);          // RNE to bf16
    return (unsigned short)(u >> 16);
}
// base offset of row r: tile g padded to (g+1)*64 cols (rows 128B-aligned)
__device__ __forceinline__ int rtp0(int r) {
    const int g = r >> 6;
    return 2048 * g * (g + 1) + (r & 63) * ((g + 1) << 6);
}
// element (r,c): 8-el chunk index XOR'd by (r&7)
__device__ __forceinline__ int rtp_off(int r, int c) {
    return rtp0(r) + (((c >> 3) ^ (r & 7)) << 3) + (c & 7);
}

// ---------------- merged prep: W->i8 | X->i8 per-row scaled | Crtp pad zero ----------
#define NW_BLK 8224            // 8224*1024 float4 = 32896*1024/4
#define NX_BLK 512             // 4 rows/block (1 wave per row)
#define NZ_BLK 2048
__global__ void prep_all(const float* __restrict__ X, const float* __restrict__ W,
                         signed char* __restrict__ Xq, signed char* __restrict__ Wq,
                         float* __restrict__ Sx, unsigned short* __restrict__ Crtp) {
    const int bid = blockIdx.x, tid = threadIdx.x;
    if (bid < NW_BLK) {                         // W quant: wq = round(w*32*127), |w|<=1/32
#pragma unroll
        for (int u = 0; u < 4; ++u) {
            const int i = bid * 1024 + u * 256 + tid;       // float4 index
            float4 v = reinterpret_cast<const float4*>(W)[i];
            const int q0 = (int)rintf(v.x * 4064.f), q1 = (int)rintf(v.y * 4064.f);
            const int q2 = (int)rintf(v.z * 4064.f), q3 = (int)rintf(v.w * 4064.f);
            reinterpret_cast<unsigned int*>(Wq)[i] =
                (q0 & 255) | ((q1 & 255) << 8) | ((q2 & 255) << 16) | ((unsigned)(q3 & 255) << 24);
        }
    } else if (bid < NW_BLK + NX_BLK) {         // X quant, per-row scale
        const int wv  = tid >> 6, ln = tid & 63;
        const int row = (bid - NW_BLK) * 4 + wv;
        const float* xr = X + (size_t)row * IN_DIM + ln * 16;
        float f[16];
#pragma unroll
        for (int u = 0; u < 4; ++u) {
            float4 v = reinterpret_cast<const float4*>(xr)[u];
            f[u * 4 + 0] = v.x; f[u * 4 + 1] = v.y; f[u * 4 + 2] = v.z; f[u * 4 + 3] = v.w;
        }
        float m = 0.f;
#pragma unroll
        for (int e = 0; e < 16; ++e) m = fmaxf(m, fabsf(f[e]));
#pragma unroll
        for (int off = 1; off < 64; off <<= 1) m = fmaxf(m, __shfl_xor(m, off));
        const float inv = m > 1e-30f ? 127.f / m : 0.f;
        unsigned int w4[4];
#pragma unroll
        for (int u = 0; u < 4; ++u) {
            const int q0 = (int)rintf(f[u * 4 + 0] * inv), q1 = (int)rintf(f[u * 4 + 1] * inv);
            const int q2 = (int)rintf(f[u * 4 + 2] * inv), q3 = (int)rintf(f[u * 4 + 3] * inv);
            w4[u] = (q0 & 255) | ((q1 & 255) << 8) | ((q2 & 255) << 16) | ((unsigned)(q3 & 255) << 24);
        }
        reinterpret_cast<uint4*>(Xq + (size_t)row * IN_DIM)[ln] =
            make_uint4(w4[0], w4[1], w4[2], w4[3]);
        if (ln == 0) Sx[row] = m / (127.f * 4064.f);        // sx * sw combined
    } else {                                    // Crtp pad zero (layout unchanged)
        const int b = bid - NW_BLK - NX_BLK;
        const int r = tid;
        const int g = r >> 6;
        const int nch = (g + 1) << 3;
        const int xm = r & 7;
        unsigned short* base = Crtp + (size_t)b * RTP_B + rtp0(r);
        const int pc = (r >> 3) ^ xm;
        for (int c = r + 1; (c >> 3) == (r >> 3); ++c) base[(pc << 3) + (c & 7)] = 0;
        const uint4 z = make_uint4(0u, 0u, 0u, 0u);
        for (int cc = (r >> 3) + 1; cc < nch; ++cc)
            *reinterpret_cast<uint4*>(&base[(cc ^ xm) << 3]) = z;
    }
}

// ---------------- Stage 1: C = dequant(Xq @ Wq^T) + bias, diag-ReLU, rtp bf16 --------
// i8 MFMA 16x16x64: BM=256, BN=128, BK=64 (one MFMA spans whole BK). 8 waves (4M x 2N),
// wave tile 64x64 = 4x4 frags. Triple-buffer ring (3 x 24KB), counted vmcnt(3),
// 1 barrier/iter, setprio. 64B i8 rows => b128 reads perfectly bank-balanced, no swizzle.
// Grid 2080 = R6's XCD mapping (measured best).
__global__ __launch_bounds__(512) void gemm1_kernel(
    const signed char* __restrict__ Xq, const signed char* __restrict__ Wq,
    const float* __restrict__ bias, const float* __restrict__ Sx,
    unsigned short* __restrict__ Crtp)
{
    __shared__ __align__(16) unsigned char lds[3 * 24576];   // per buf: A 16KB | B 8KB

    const int lin = blockIdx.x;
    const int x   = lin & 7;                       // XCD (round-robin dispatch)
    const int j   = lin >> 3;                      // 0..259 within XCD
    const int rtile = ((x & 1) << 2) + (j & 3);    // 0..7
    const int panel = (x >> 1) * 65 + (j >> 2);    // 0..259
    if (panel >= 257) return;
    const int row0 = rtile << 8;
    const int col0 = panel << 7;

    const int tid  = threadIdx.x;
    const int lane = tid & 63;
    const int wid  = tid >> 6;                     // 0..7
    const int wr   = wid >> 1;                     // 0..3
    const int wc   = wid & 1;                      // 0..1
    const int lr16 = lane & 15;
    const int kq   = lane >> 4;                    // K-quarter 0..3

    // staging: per K-tile wave stages A rows [32wid,32wid+32) (2 GLD16) + B rows
    // [16wid,16wid+16) (1 GLD16). lane -> row lane>>2, 16B chunk lane&3 (linear).
    const int srow = lane >> 2;
    const int sch  = lane & 3;
    const signed char* gA = Xq + (size_t)(row0 + (wid << 5) + srow) * IN_DIM + (sch << 4);
    const signed char* gB = Wq + (size_t)(col0 + (wid << 4) + srow) * IN_DIM + (sch << 4);

#define STAGE(kt, bufo)                                                          \
    {                                                                            \
        GLD16(gA + ((kt) << 6),                        &lds[(bufo) + (wid << 11)]); \
        GLD16(gA + (size_t)16 * IN_DIM + ((kt) << 6),  &lds[(bufo) + (wid << 11) + 1024]); \
        GLD16(gB + ((kt) << 6),                        &lds[(bufo) + 16384 + (wid << 10)]); \
    }

    i32x4 acc[4][4];
#pragma unroll
    for (int m = 0; m < 4; ++m)
#pragma unroll
        for (int n = 0; n < 4; ++n) acc[m][n] = (i32x4){0, 0, 0, 0};

    int o0 = 0, o1 = 24576, o2 = 49152;
    STAGE(0, o0);
    STAGE(1, o1);

    for (int it = 0; it < 16; ++it) {
        if (it < 15) asm volatile("s_waitcnt vmcnt(3)" ::: "memory");
        else         asm volatile("s_waitcnt vmcnt(0)" ::: "memory");
        __builtin_amdgcn_s_barrier();
        asm volatile("" ::: "memory");             // keep ds_reads below the barrier

        const int cb = o0;
        i32x4 av[4], bv[4];
#pragma unroll
        for (int m = 0; m < 4; ++m) {
            const int r = (wr << 6) + (m << 4) + lr16;
            av[m] = *reinterpret_cast<const i32x4*>(&lds[cb + (r << 6) + (kq << 4)]);
        }
#pragma unroll
        for (int n = 0; n < 4; ++n) {
            const int r = (wc << 6) + (n << 4) + lr16;
            bv[n] = *reinterpret_cast<const i32x4*>(&lds[cb + 16384 + (r << 6) + (kq << 4)]);
        }
        if (it < 14) STAGE(it + 2, o2);            // prefetch depth 2
        __builtin_amdgcn_s_setprio(1);
#pragma unroll
        for (int m = 0; m < 4; ++m)
#pragma unroll
            for (int n = 0; n < 4; ++n)
                acc[m][n] = __builtin_amdgcn_mfma_i32_16x16x64_i8(av[m], bv[n], acc[m][n], 0, 0, 0);
        __builtin_amdgcn_s_setprio(0);

        const int t = o0; o0 = o1; o1 = o2; o2 = t;   // rotate ring
    }
#undef STAGE

    // per-row dequant scales for this lane's 16 output rows
    float sc[4][4];
#pragma unroll
    for (int m = 0; m < 4; ++m)
#pragma unroll
        for (int q = 0; q < 4; ++q)
            sc[m][q] = Sx[row0 + (wr << 6) + (m << 4) + (kq << 2) + q];

    // epilogue: D col = lane&15, row = (lane>>4)*4 + reg
#pragma unroll
    for (int n = 0; n < 4; ++n) {
        const int p = col0 + (wc << 6) + (n << 4) + lr16;     // packed tril index
        const float t = sqrtf((float)(8 * p + 1));
        const int rt = (int)((t - 1.0f) * 0.5f + 0.001f);     // tril row
        const int ct = p - ((rt * (rt + 1)) >> 1);            // tril col
        const int off = rtp_off(rt, ct);                      // swizzled position
        const bool diag = (ct == rt);
        const float bvs = bias[p];
#pragma unroll
        for (int m = 0; m < 4; ++m) {
#pragma unroll
            for (int q = 0; q < 4; ++q) {
                const int brow = row0 + (wr << 6) + (m << 4) + (kq << 2) + q;
                float v = (float)acc[m][n][q] * sc[m][q] + bvs;
                if (diag) v = fmaxf(v, 0.f);
                Crtp[(size_t)brow * RTP_B + off] = f2bf(v);
            }
        }
    }
}

// ---------------- Stage 2: O[b] = L_b @ L_b^T, LDS-staged (80 KB -> 2 blocks/CU) ------
__global__ __launch_bounds__(256) void syrk_kernel(
    const unsigned short* __restrict__ Crtp, float* __restrict__ O)
{
    __shared__ unsigned short Lt[RTP_B];       // 81920 B exactly -> 2 blocks/CU
    const int tid  = threadIdx.x;
    const int lane = tid & 63;
    const int wid  = tid >> 6;
    const int b    = blockIdx.x;
    const unsigned short* Cb = Crtp + (size_t)b * RTP_B;

#pragma unroll
    for (int i = 0; i < 20; ++i) {
        const int g = wid * 20 + i;
        GLD16(Cb + g * 512 + (lane << 3), &Lt[g * 512]);
    }
    __syncthreads();

    const int lr16 = lane & 15;
    const int kc   = lane >> 4;
    float* Ob = O + (size_t)b * (M_DIM * M_DIM);

    const unsigned char LIST[4][5] = {
        {0x33, 0x22, 0x00, 0x00, 0x00},
        {0x23, 0x32, 0x01, 0x10, 0x00},
        {0x11, 0x12, 0x21, 0x02, 0x00},
        {0x13, 0x31, 0x03, 0x30, 0x20}};
    const int CNT[4] = {3, 4, 4, 5};
    const int cnt = CNT[wid];

    for (int tt = 0; tt < cnt; ++tt) {
        const int code = LIST[wid][tt];
        const int ti = code >> 4, tj = code & 15;

        int baseA[4], xA[4], baseB[4], xB[4];
#pragma unroll
        for (int m = 0; m < 4; ++m) {
            const int ia = (ti << 6) + (m << 4) + lr16;
            const int jb = (tj << 6) + (m << 4) + lr16;
            baseA[m] = rtp0(ia); xA[m] = ia & 7;
            baseB[m] = rtp0(jb); xB[m] = jb & 7;
        }
        f32x4 acc[4][4];
#pragma unroll
        for (int m = 0; m < 4; ++m)
#pragma unroll
            for (int n = 0; n < 4; ++n) acc[m][n] = (f32x4){0.f, 0.f, 0.f, 0.f};

        const int kmax = ti < tj ? ti : tj;
        for (int kt = 0; kt <= kmax; ++kt) {
#pragma unroll
            for (int s = 0; s < 2; ++s) {
                const int cidx = (kt << 3) + (s << 2) + kc;   // 8-el chunk index
                short8 a[4], bb[4];
#pragma unroll
                for (int m = 0; m < 4; ++m)
                    a[m] = *reinterpret_cast<const short8*>(&Lt[baseA[m] + ((cidx ^ xA[m]) << 3)]);
#pragma unroll
                for (int n = 0; n < 4; ++n)
                    bb[n] = *reinterpret_cast<const short8*>(&Lt[baseB[n] + ((cidx ^ xB[n]) << 3)]);
#pragma unroll
                for (int m = 0; m < 4; ++m)
#pragma unroll
                    for (int n = 0; n < 4; ++n)
                        acc[m][n] = __builtin_amdgcn_mfma_f32_16x16x32_bf16(a[m], bb[n], acc[m][n], 0, 0, 0);
            }
        }
#pragma unroll
        for (int m = 0; m < 4; ++m) {
            const int i0 = (ti << 6) + (m << 4) + (kc << 2);
#pragma unroll
            for (int n = 0; n < 4; ++n) {
                const int j = (tj << 6) + (n << 4) + lr16;
#pragma unroll
                for (int q = 0; q < 4; ++q)
                    __builtin_nontemporal_store(acc[m][n][q], &Ob[(size_t)(i0 + q) * M_DIM + j]);
            }
        }
    }
}

extern "C" void kernel_launch(void* const* d_in, const int* in_sizes, int n_in,
                              void* d_out, int out_size, void* d_ws, size_t ws_size,
                              hipStream_t stream)
{
    (void)in_sizes; (void)n_in; (void)out_size; (void)ws_size;
    const float* x    = (const float*)d_in[0];
    const float* W    = (const float*)d_in[1];
    const float* bias = (const float*)d_in[2];
    float* O = (float*)d_out;

    char* ws = (char*)d_ws;
    unsigned short* Crtp = (unsigned short*)ws;
    signed char*    Wq   = (signed char*)(ws + CRTP_BYTES);
    signed char*    Xq   = (signed char*)(ws + CRTP_BYTES + WQ_BYTES);
    float*          Sx   = (float*)(ws + CRTP_BYTES + WQ_BYTES + XQ_BYTES);

    prep_all<<<dim3(NW_BLK + NX_BLK + NZ_BLK), dim3(256), 0, stream>>>(
        x, W, Xq, Wq, Sx, Crtp);
    gemm1_kernel<<<dim3(2080), dim3(512), 0, stream>>>(Xq, Wq, bias, Sx, Crtp);
    syrk_kernel<<<dim3(B_DIM), dim3(256), 0, stream>>>(Crtp, O);
}